// Round 6
// baseline (237.498 us; speedup 1.0000x reference)
//
#include <hip/hip_runtime.h>
#include <stdint.h>

#define DIM   2048
#define LSEQ  2048
#define BATCH 2
#define NH    32
#define NKV   8
#define HD    64
#define M_ROWS (BATCH*LSEQ)       // 4096
#define NQKV  (DIM + 2*NKV*HD)    // 3072
#define KOFF  DIM                 // 2048
#define VOFF  (DIM + NKV*HD)      // 2560

typedef __attribute__((ext_vector_type(8))) __bf16 bf16x8;
typedef __attribute__((ext_vector_type(8))) unsigned short u16x8;
typedef __attribute__((ext_vector_type(4))) float f32x4;

// hardware RNE f32->bf16 (harness-verified rounds 2-5)
__device__ __forceinline__ unsigned short f2bf(float f) {
  union { __bf16 h; unsigned short u; } v;
  v.h = (__bf16)f;
  return v.u;
}
__device__ __forceinline__ float bf2f(unsigned short h) {
  union { unsigned u; float f; } v; v.u = ((unsigned)h) << 16;
  return v.f;
}

__device__ __forceinline__ void gload_lds16(const void* g, void* l) {
  __builtin_amdgcn_global_load_lds(
      (__attribute__((address_space(1))) unsigned int*)g,
      (__attribute__((address_space(3))) unsigned int*)l, 16, 0, 0);
}

#define BARS { __builtin_amdgcn_s_barrier(); __builtin_amdgcn_sched_barrier(0); }

// ---------------- fp32 -> bf16 convert (vectorized) ----------------
__global__ void k_cvt_x(const float* __restrict__ in, unsigned short* __restrict__ out, int n4) {
  int i = blockIdx.x * blockDim.x + threadIdx.x;
  if (i >= n4) return;
  float4 v = ((const float4*)in)[i];
  ushort4 o;
  o.x = f2bf(v.x); o.y = f2bf(v.y); o.z = f2bf(v.z); o.w = f2bf(v.w);
  ((ushort4*)out)[i] = o;
}

// ---------------- transpose + cast + scale: out[n][k] = bf16(scale*in[k][n]) ----------------
__global__ void k_transpose_bf16(const float* __restrict__ in, unsigned short* __restrict__ out,
                                 int K, int N, float scale) {
  __shared__ float tile[32][33];
  int n0 = blockIdx.x * 32, k0 = blockIdx.y * 32;
  int tx = threadIdx.x, ty = threadIdx.y;
  #pragma unroll
  for (int i = ty; i < 32; i += 8)
    tile[i][tx] = in[(long)(k0 + i) * N + n0 + tx];
  __syncthreads();
  #pragma unroll
  for (int i = ty; i < 32; i += 8)
    out[(long)(n0 + i) * K + k0 + tx] = f2bf(scale * tile[tx][i]);
}

// ---------------- transpose V section of qkv -> vT, k-PERMUTED columns ----------------
// Within each 32-wide k-block, column position e holds original k = tx with
// e = 8*((tx>>2)&3) + 4*(tx>>4) + (tx&3). This matches flash v15's in-register-P
// A-fragment k-order (slot (fg,j) <-> k = (j>=4)*16 + 4*fg + (j&3)), so PV's
// contraction pairs A and B at identical k despite the swapped-QK lane-local P.
__global__ void k_transpose_v(const unsigned short* __restrict__ qkv,
                              unsigned short* __restrict__ vT) {
  __shared__ unsigned short tile[32][33];
  int c0 = blockIdx.x * 32;   // within 512 (= g*64+d)
  int l0 = blockIdx.y * 32;
  int b  = blockIdx.z;
  int tx = threadIdx.x, ty = threadIdx.y;
  #pragma unroll
  for (int i = ty; i < 32; i += 8)
    tile[i][tx] = qkv[((long)b * LSEQ + l0 + i) * NQKV + VOFF + c0 + tx];
  __syncthreads();
  int e = 8 * ((tx >> 2) & 3) + 4 * (tx >> 4) + (tx & 3);
  #pragma unroll
  for (int i = ty; i < 32; i += 8)
    vT[((long)b * 512 + c0 + i) * LSEQ + l0 + e] = tile[tx][i];
}

// ---------------- RoPE tables ----------------
__global__ void k_rope_table(float* __restrict__ cosT, float* __restrict__ sinT) {
  int i = blockIdx.x * 256 + threadIdx.x;  // < LSEQ*32
  int t = i >> 5, j = i & 31;
  float inv = powf(10000.0f, -(float)j / 32.0f);
  float fr = (float)t * inv;
  cosT[i] = cosf(fr);
  sinT[i] = sinf(fr);
}

// ---------------- RoPE apply in-place on qkv (Q: 32 heads, K: 8 heads) ----------------
__global__ void k_rope_apply(unsigned short* __restrict__ qkv, const float* __restrict__ cosT,
                             const float* __restrict__ sinT) {
  long i = (long)blockIdx.x * 256 + threadIdx.x;  // < M_ROWS*40*32
  int j = (int)(i & 31);
  long rem = i >> 5;
  int hs = (int)(rem % 40);
  long row = rem / 40;
  int t = (int)(row & (LSEQ - 1));
  long col = (hs < 32) ? (long)hs * 64 + j : (long)KOFF + (long)(hs - 32) * 64 + j;
  long base = row * NQKV + col;
  float v0 = bf2f(qkv[base]), v1 = bf2f(qkv[base + 32]);
  float c = cosT[t * 32 + j], s = sinT[t * 32 + j];
  qkv[base]      = f2bf(v0 * c - v1 * s);
  qkv[base + 32] = f2bf(v1 * c + v0 * s);
}

// ---------------- GEMM v3: 8-phase counted-vmcnt schedule (round-5, measured ~= 2-phase) ----------------
template<bool BF16OUT>
__global__ __launch_bounds__(512, 2) void k_gemm_8ph(
    const unsigned short* __restrict__ A, const unsigned short* __restrict__ Bt,
    void* __restrict__ Cv, int M, int N, int K, int nbn) {
  __shared__ __align__(16) char LDS[98304];   // A: [0,65536) ; B: [65536, 98304)
  int t = threadIdx.x;
  int lane = t & 63, wave = t >> 6;
  int fr = lane & 15, fg = lane >> 4;
  int wm = wave >> 2, wn = wave & 3;          // 2 M-waves x 4 N-waves
  int sw8 = (fr & 7) << 4;

  int nwg = (int)gridDim.x;
  int id = (int)blockIdx.x;
  int swz = (id & 7) * (nwg >> 3) + (id >> 3);
  long rowA = (long)(swz / nbn) * 256;
  long rowB = (long)(swz % nbn) * 128;

  long K2 = (long)K * 2;
  int scol = ((t & 7) * 16) ^ (((t >> 3) & 7) << 4);
  const char* Ab = (const char*)A;
  const char* Bb = (const char*)Bt;

  auto stageAh = [&](int kt, int h, int b) {
    #pragma unroll
    for (int q = 0; q < 2; q++)
      gload_lds16(Ab + (rowA + h * 128 + q * 64 + (t >> 3)) * K2 + kt * 128 + scol,
                  LDS + b * 32768 + h * 16384 + q * 8192 + t * 16);
  };
  auto stageBh = [&](int kt, int h, int b) {
    gload_lds16(Bb + (rowB + h * 64 + (t >> 3)) * K2 + kt * 128 + scol,
                LDS + 65536 + b * 16384 + h * 8192 + t * 16);
  };

  f32x4 acc[8][2] = {};

  auto rdA = [&](bf16x8 (&af)[4][2], int b, int qm) {
    #pragma unroll
    for (int i = 0; i < 4; i++) {
      #pragma unroll
      for (int ks = 0; ks < 2; ks++)
        af[i][ks] = *(const bf16x8*)(LDS + b * 32768 +
            (wm * 128 + qm * 64 + i * 16 + fr) * 128 + ((ks * 64 + fg * 16) ^ sw8));
    }
  };
  auto rdB = [&](bf16x8 (&bv)[2], int b, int qn) {
    #pragma unroll
    for (int ks = 0; ks < 2; ks++)
      bv[ks] = *(const bf16x8*)(LDS + 65536 + b * 16384 +
          (wn * 32 + qn * 16 + fr) * 128 + ((ks * 64 + fg * 16) ^ sw8));
  };
  auto quad = [&](bf16x8 (&af)[4][2], bf16x8 (&bv)[2], int qi, int qj) {
    __builtin_amdgcn_s_setprio(1);
    #pragma unroll
    for (int i = 0; i < 4; i++) {
      #pragma unroll
      for (int ks = 0; ks < 2; ks++)
        acc[qi * 4 + i][qj] =
            __builtin_amdgcn_mfma_f32_16x16x32_bf16(af[i][ks], bv[ks], acc[qi * 4 + i][qj], 0, 0, 0);
    }
    __builtin_amdgcn_s_setprio(0);
  };

  int NT = K >> 6;

  stageAh(0, 0, 0); stageAh(0, 1, 0); stageBh(0, 0, 0); stageBh(0, 1, 0);
  stageAh(1, 0, 1);
  __builtin_amdgcn_sched_barrier(0);
  asm volatile("s_waitcnt vmcnt(2)" ::: "memory");
  BARS;

  for (int u = 0; u < NT; u += 2) {
    bool pfw = (u + 2) < NT;
    bool pfx = (u + 3) < NT;
    bf16x8 a0[4][2], a1[4][2], b0[2], b1[2];

    // ---- K-tile u (buf0) ----
    rdA(a0, 0, 0); rdB(b0, 0, 0);
    stageAh(u + 1, 1, 1);
    BARS; quad(a0, b0, 0, 0); BARS;
    rdB(b1, 0, 1);
    stageBh(u + 1, 0, 1);
    BARS; quad(a0, b1, 0, 1); BARS;
    rdA(a1, 0, 1);
    stageBh(u + 1, 1, 1);
    BARS; quad(a1, b0, 1, 0); BARS;
    if (pfw) {
      stageAh(u + 2, 0, 0);
      __builtin_amdgcn_sched_barrier(0);
      asm volatile("s_waitcnt vmcnt(2)" ::: "memory");
    } else {
      asm volatile("s_waitcnt vmcnt(0)" ::: "memory");
    }
    BARS; quad(a1, b1, 1, 1); BARS;

    // ---- K-tile v = u+1 (buf1) ----
    rdA(a0, 1, 0); rdB(b0, 1, 0);
    if (pfw) stageAh(u + 2, 1, 0);
    BARS; quad(a0, b0, 0, 0); BARS;
    rdB(b1, 1, 1);
    if (pfw) stageBh(u + 2, 0, 0);
    BARS; quad(a0, b1, 0, 1); BARS;
    rdA(a1, 1, 1);
    if (pfw) stageBh(u + 2, 1, 0);
    BARS; quad(a1, b0, 1, 0); BARS;
    if (pfx) {
      stageAh(u + 3, 0, 1);
      __builtin_amdgcn_sched_barrier(0);
      asm volatile("s_waitcnt vmcnt(2)" ::: "memory");
    } else {
      asm volatile("s_waitcnt vmcnt(0)" ::: "memory");
    }
    BARS; quad(a1, b1, 1, 1); BARS;
  }

  #pragma unroll
  for (int ii = 0; ii < 8; ii++) {
    #pragma unroll
    for (int jj = 0; jj < 2; jj++) {
      #pragma unroll
      for (int r = 0; r < 4; r++) {
        long row = rowA + wm * 128 + ii * 16 + fg * 4 + r;
        long col = rowB + wn * 32 + jj * 16 + fr;
        if (BF16OUT) ((unsigned short*)Cv)[row * N + col] = f2bf(acc[ii][jj][r]);
        else         ((float*)Cv)[row * N + col] = acc[ii][jj][r];
      }
    }
  }
}

// ---------------- flash attention v15: swapped QK^T -> in-register P ----------------
// Round-6: P's LDS round-trip (64 scalar ds_write + 8 ds_read per wave-iter, 32KB Pl,
// the 3.34M bank-conflict source) is deleted by computing mfma(K,Q) instead of mfma(Q,K):
// A/B fragments of 16x16x32 share the (lane&15, fg*8+j) layout, so the swap is free and
// st[s][r] = S[k=kbase+s*16+fg*4+r][q=qbase+fr] -- P is lane-local per q-column.
// Each lane keeps its own 32 P values, packs to 4x bf16x8 in-register (A-frag slot
// (fg,j) <-> k = (j>=4)*16+4*fg+(j&3)); V's k-order is permuted to match in
// k_transpose_v, so PV contracts correctly with zero cross-lane traffic.
// LDS 80KB -> 48KB -> 3 blocks/CU; l is per-lane scalar (2 shfl at epilogue).
// Staging: V issued right after B1 (all prior-PV readers synced), K after B2.
__global__ __launch_bounds__(256, 3) void k_flash_attn12(
    const unsigned short* __restrict__ qkv, const unsigned short* __restrict__ vT,
    unsigned short* __restrict__ attn) {
  int g0 = (int)blockIdx.x;
  int hb = g0 & 63;
  int h = hb & 31, b = hb >> 5;
  int qt = 15 - (g0 >> 6);            // heavy blocks first (backfill smooths the tail)
  int g = h >> 2;
  int t = threadIdx.x, lane = t & 63, wave = t >> 6;
  int fr = lane & 15, fg = lane >> 4;

  __shared__ __align__(16) char KT[16384];              // 16KB: K tile [128 rows][128B], swz
  __shared__ __align__(16) char VT2[2][16384];          // 32KB: V tile [64 rows][256B], swz, dbuf
  long rowbase = (long)b * LSEQ;

  int qbaseA = qt * 128 + wave * 32;
  int qbaseB = qbaseA + 16;

  const unsigned short* qpA = &qkv[(rowbase + qbaseA + fr) * NQKV + h * 64 + fg * 8];
  const unsigned short* qpB = &qkv[(rowbase + qbaseB + fr) * NQKV + h * 64 + fg * 8];
  bf16x8 qfA0 = *(const bf16x8*)(qpA);
  bf16x8 qfA1 = *(const bf16x8*)(qpA + 32);
  bf16x8 qfB0 = *(const bf16x8*)(qpB);
  bf16x8 qfB1 = *(const bf16x8*)(qpB + 32);

  int kcb = ((t & 7) * 16) ^ (((t >> 3) & 7) << 4);    // K: 128B rows, row = p*32 + (t>>3)
  int vcb = ((t & 15) * 16) ^ (((t >> 4) & 7) << 4);   // V: 256B rows, row = p*16 + (t>>4)

  const char* kgb = (const char*)qkv;
  const char* vgb = (const char*)vT;
  long ksrc0 = ((rowbase) * (long)NQKV + KOFF + (long)g * 64) * 2;
  long vsrc0 = (((long)(b * 512 + g * 64)) * LSEQ) * 2;

  auto stageK = [&](int kbase) {
    #pragma unroll
    for (int p = 0; p < 4; p++) {
      int krow = p * 32 + (t >> 3);
      gload_lds16(kgb + ksrc0 + (long)(kbase + krow) * (NQKV * 2) + kcb,
                  KT + p * 4096 + t * 16);
    }
  };
  auto stageV = [&](int kbase, char* dst) {
    #pragma unroll
    for (int p = 0; p < 4; p++) {
      int vrow = p * 16 + (t >> 4);
      gload_lds16(vgb + vsrc0 + (long)vrow * (LSEQ * 2) + kbase * 2 + vcb,
                  dst + p * 4096 + t * 16);
    }
  };

  stageK(0);
  stageV(0, VT2[0]);

  f32x4 poA[4] = {}, poB[4] = {};
  float lA = 0.f, lB = 0.f;   // per-lane partial denominators for q = qbase+fr

  int sw8 = (fr & 7) << 4;

  for (int kt = 0; kt <= qt; kt++) {
    int kbase = kt * 128;
    __syncthreads();   // B1: staged K/V landed; all waves' prev-iter LDS reads done

    // V restage WAR-safe at B1 (prev PV readers of this buffer synced); full-iter cover
    if (kt < qt) stageV(kbase + 128, VT2[(kt + 1) & 1]);

    f32x4 stA[8], stB[8];
    __builtin_amdgcn_s_setprio(1);
    #pragma unroll
    for (int s = 0; s < 8; s++) {
      const char* kr = KT + ((s * 16 + fr) << 7);
      bf16x8 kf0 = *(const bf16x8*)(kr + ((fg * 16) ^ sw8));
      bf16x8 kf1 = *(const bf16x8*)(kr + ((fg * 16 + 64) ^ sw8));
      f32x4 a = {};
      a = __builtin_amdgcn_mfma_f32_16x16x32_bf16(kf0, qfA0, a, 0, 0, 0);
      a = __builtin_amdgcn_mfma_f32_16x16x32_bf16(kf1, qfA1, a, 0, 0, 0);
      stA[s] = a;
      f32x4 c = {};
      c = __builtin_amdgcn_mfma_f32_16x16x32_bf16(kf0, qfB0, c, 0, 0, 0);
      c = __builtin_amdgcn_mfma_f32_16x16x32_bf16(kf1, qfB1, c, 0, 0, 0);
      stB[s] = c;
    }
    __builtin_amdgcn_s_setprio(0);
    __syncthreads();   // B2: all waves' K ds_reads retired -> K restage safe

    if (kt < qt) stageK(kbase + 128);   // lands by next B1; softmax+PV cover

    if (kt == qt) {   // diagonal tile: causal mask (k = kbase+s*16+fg*4+r, q = qbase+fr)
      #pragma unroll
      for (int s = 0; s < 8; s++) {
        #pragma unroll
        for (int r = 0; r < 4; r++) {
          int kp = kbase + s * 16 + fg * 4 + r;
          if (kp > qbaseA + fr) stA[s][r] = -1e30f;
          if (kp > qbaseB + fr) stB[s][r] = -1e30f;
        }
      }
    }

    // softmax (static-max, scores pre-scaled into exp2 domain via wq) + in-register pack
    bf16x8 paA[4], paB[4];
    #pragma unroll
    for (int km = 0; km < 4; km++) {
      float pe[4], pq[4];
      #pragma unroll
      for (int r = 0; r < 4; r++) {
        pe[r] = exp2f(stA[2 * km][r]);        // k32 = 4*fg + r      (slots j=0..3)
        pq[r] = exp2f(stA[2 * km + 1][r]);    // k32 = 16 + 4*fg + r (slots j=4..7)
        lA += pe[r] + pq[r];
      }
      union { unsigned u[4]; bf16x8 v; } pk_;
      pk_.u[0] = ((unsigned)f2bf(pe[1]) << 16) | f2bf(pe[0]);
      pk_.u[1] = ((unsigned)f2bf(pe[3]) << 16) | f2bf(pe[2]);
      pk_.u[2] = ((unsigned)f2bf(pq[1]) << 16) | f2bf(pq[0]);
      pk_.u[3] = ((unsigned)f2bf(pq[3]) << 16) | f2bf(pq[2]);
      paA[km] = pk_.v;
    }
    #pragma unroll
    for (int km = 0; km < 4; km++) {
      float pe[4], pq[4];
      #pragma unroll
      for (int r = 0; r < 4; r++) {
        pe[r] = exp2f(stB[2 * km][r]);
        pq[r] = exp2f(stB[2 * km + 1][r]);
        lB += pe[r] + pq[r];
      }
      union { unsigned u[4]; bf16x8 v; } pk_;
      pk_.u[0] = ((unsigned)f2bf(pe[1]) << 16) | f2bf(pe[0]);
      pk_.u[1] = ((unsigned)f2bf(pe[3]) << 16) | f2bf(pe[2]);
      pk_.u[2] = ((unsigned)f2bf(pq[1]) << 16) | f2bf(pq[0]);
      pk_.u[3] = ((unsigned)f2bf(pq[3]) << 16) | f2bf(pq[2]);
      paB[km] = pk_.v;
    }

    const char* Vb = VT2[kt & 1];
    __builtin_amdgcn_s_setprio(1);
    #pragma unroll
    for (int km = 0; km < 4; km++) {
      #pragma unroll
      for (int dt = 0; dt < 4; dt++) {
        const char* vr = Vb + ((dt * 16 + fr) << 8);
        bf16x8 vf = *(const bf16x8*)(vr + ((km * 64 + fg * 16) ^ sw8));
        poA[dt] = __builtin_amdgcn_mfma_f32_16x16x32_bf16(paA[km], vf, poA[dt], 0, 0, 0);
        poB[dt] = __builtin_amdgcn_mfma_f32_16x16x32_bf16(paB[km], vf, poB[dt], 0, 0, 0);
      }
    }
    __builtin_amdgcn_s_setprio(0);
    // no trailing barrier: next B1 orders LDS reads vs. restaging
  }

  // denominator: reduce per-lane partials over the fg-group (lanes fr, fr+16, fr+32, fr+48)
  lA += __shfl_xor(lA, 16, 64); lA += __shfl_xor(lA, 32, 64);
  lB += __shfl_xor(lB, 16, 64); lB += __shfl_xor(lB, 32, 64);

  // po[dt][r] is O[q = qbase + fg*4 + r][d = dt*16 + fr]; l for q-local i lives on lanes
  // with fr == i -> fetch via shfl from lane fg*4+r (fg=0 copy).
  #pragma unroll
  for (int r = 0; r < 4; r++) {
    float liA = 1.0f / __shfl(lA, fg * 4 + r, 64);
    float liB = 1.0f / __shfl(lB, fg * 4 + r, 64);
    #pragma unroll
    for (int dt = 0; dt < 4; dt++) {
      attn[(rowbase + qbaseA + fg * 4 + r) * DIM + h * 64 + dt * 16 + fr] = f2bf(poA[dt][r] * liA);
      attn[(rowbase + qbaseB + fg * 4 + r) * DIM + h * 64 + dt * 16 + fr] = f2bf(poB[dt][r] * liB);
    }
  }
}

extern "C" void kernel_launch(void* const* d_in, const int* in_sizes, int n_in,
                              void* d_out, int out_size, void* d_ws, size_t ws_size,
                              hipStream_t stream) {
  const float* x  = (const float*)d_in[0];
  const float* wq = (const float*)d_in[1];
  const float* wk = (const float*)d_in[2];
  const float* wv = (const float*)d_in[3];
  const float* wo = (const float*)d_in[4];

  char* ws = (char*)d_ws;
  unsigned short* xb    = (unsigned short*)(ws);                 // 16.78 MB (reused as vT later)
  unsigned short* wqkvT = (unsigned short*)(ws + 16777216);      // 12.58 MB [3072][2048]
  unsigned short* woT   = (unsigned short*)(ws + 29360128);      //  8.39 MB [2048][2048]
  unsigned short* qkv   = (unsigned short*)(ws + 37748736);      // 25.17 MB [4096][3072]
  unsigned short* attn  = (unsigned short*)(ws + 62914560);      // 16.78 MB [4096][2048]
  float* cosT           = (float*)(ws + 79691776);               // 256 KB
  float* sinT           = (float*)(ws + 79953920);               // 256 KB
  unsigned short* vT    = xb;                                    // alias: xb dead after QKV GEMM

  const float C2 = 0.125f * 1.44269504f;   // 1/sqrt(64) * log2(e), folded into wq

  k_cvt_x<<<8192, 256, 0, stream>>>(x, xb, M_ROWS * DIM / 4);
  dim3 tb(32, 8);
  k_transpose_bf16<<<dim3(DIM/32, DIM/32), tb, 0, stream>>>(wq, wqkvT, DIM, DIM, C2);
  k_transpose_bf16<<<dim3(512/32, DIM/32), tb, 0, stream>>>(wk, wqkvT + (long)2048*2048, DIM, 512, 1.0f);
  k_transpose_bf16<<<dim3(512/32, DIM/32), tb, 0, stream>>>(wv, wqkvT + (long)2560*2048, DIM, 512, 1.0f);
  k_transpose_bf16<<<dim3(DIM/32, DIM/32), tb, 0, stream>>>(wo, woT, DIM, DIM, 1.0f);
  k_rope_table<<<(LSEQ*32)/256, 256, 0, stream>>>(cosT, sinT);

  k_gemm_8ph<true><<<(M_ROWS/256)*(NQKV/128), 512, 0, stream>>>(xb, wqkvT, qkv, M_ROWS, NQKV, DIM, NQKV/128);
  k_rope_apply<<<(M_ROWS*40*32)/256, 256, 0, stream>>>(qkv, cosT, sinT);
  k_transpose_v<<<dim3(16, 64, 2), tb, 0, stream>>>(qkv, vT);
  k_flash_attn12<<<1024, 256, 0, stream>>>(qkv, vT, attn);
  k_gemm_8ph<false><<<(M_ROWS/256)*(DIM/128), 512, 0, stream>>>(attn, woT, d_out, M_ROWS, DIM, DIM, DIM/128);
}

// Round 7
// 215.505 us; speedup vs baseline: 1.1021x; 1.1021x over previous
//
#include <hip/hip_runtime.h>
#include <stdint.h>

#define DIM   2048
#define LSEQ  2048
#define BATCH 2
#define NH    32
#define NKV   8
#define HD    64
#define M_ROWS (BATCH*LSEQ)       // 4096
#define NQKV  (DIM + 2*NKV*HD)    // 3072
#define KOFF  DIM                 // 2048
#define VOFF  (DIM + NKV*HD)      // 2560

typedef __attribute__((ext_vector_type(8))) __bf16 bf16x8;
typedef __attribute__((ext_vector_type(8))) unsigned short u16x8;
typedef __attribute__((ext_vector_type(4))) float f32x4;

// hardware RNE f32->bf16 (harness-verified rounds 2-6)
__device__ __forceinline__ unsigned short f2bf(float f) {
  union { __bf16 h; unsigned short u; } v;
  v.h = (__bf16)f;
  return v.u;
}
__device__ __forceinline__ float bf2f(unsigned short h) {
  union { unsigned u; float f; } v; v.u = ((unsigned)h) << 16;
  return v.f;
}

__device__ __forceinline__ void gload_lds16(const void* g, void* l) {
  __builtin_amdgcn_global_load_lds(
      (__attribute__((address_space(1))) unsigned int*)g,
      (__attribute__((address_space(3))) unsigned int*)l, 16, 0, 0);
}

#define BARS { __builtin_amdgcn_s_barrier(); __builtin_amdgcn_sched_barrier(0); }

// ---------------- fp32 -> bf16 convert (vectorized) ----------------
__global__ void k_cvt_x(const float* __restrict__ in, unsigned short* __restrict__ out, int n4) {
  int i = blockIdx.x * blockDim.x + threadIdx.x;
  if (i >= n4) return;
  float4 v = ((const float4*)in)[i];
  ushort4 o;
  o.x = f2bf(v.x); o.y = f2bf(v.y); o.z = f2bf(v.z); o.w = f2bf(v.w);
  ((ushort4*)out)[i] = o;
}

// ---------------- transpose + cast + scale: out[n][k] = bf16(scale*in[k][n]) ----------------
__global__ void k_transpose_bf16(const float* __restrict__ in, unsigned short* __restrict__ out,
                                 int K, int N, float scale) {
  __shared__ float tile[32][33];
  int n0 = blockIdx.x * 32, k0 = blockIdx.y * 32;
  int tx = threadIdx.x, ty = threadIdx.y;
  #pragma unroll
  for (int i = ty; i < 32; i += 8)
    tile[i][tx] = in[(long)(k0 + i) * N + n0 + tx];
  __syncthreads();
  #pragma unroll
  for (int i = ty; i < 32; i += 8)
    out[(long)(n0 + i) * K + k0 + tx] = f2bf(scale * tile[tx][i]);
}

// ---------------- transpose V section of qkv -> vT, k-PERMUTED columns ----------------
// Within each 32-wide k-block, column position e holds original k = tx with
// e = 8*((tx>>2)&3) + 4*(tx>>4) + (tx&3). This matches flash's in-register-P
// A-fragment k-order (slot (fg,j) <-> k = (j>=4)*16 + 4*fg + (j&3)), so PV's
// contraction pairs A and B at identical k despite the swapped-QK lane-local P.
__global__ void k_transpose_v(const unsigned short* __restrict__ qkv,
                              unsigned short* __restrict__ vT) {
  __shared__ unsigned short tile[32][33];
  int c0 = blockIdx.x * 32;   // within 512 (= g*64+d)
  int l0 = blockIdx.y * 32;
  int b  = blockIdx.z;
  int tx = threadIdx.x, ty = threadIdx.y;
  #pragma unroll
  for (int i = ty; i < 32; i += 8)
    tile[i][tx] = qkv[((long)b * LSEQ + l0 + i) * NQKV + VOFF + c0 + tx];
  __syncthreads();
  int e = 8 * ((tx >> 2) & 3) + 4 * (tx >> 4) + (tx & 3);
  #pragma unroll
  for (int i = ty; i < 32; i += 8)
    vT[((long)b * 512 + c0 + i) * LSEQ + l0 + e] = tile[tx][i];
}

// ---------------- RoPE tables ----------------
__global__ void k_rope_table(float* __restrict__ cosT, float* __restrict__ sinT) {
  int i = blockIdx.x * 256 + threadIdx.x;  // < LSEQ*32
  int t = i >> 5, j = i & 31;
  float inv = powf(10000.0f, -(float)j / 32.0f);
  float fr = (float)t * inv;
  cosT[i] = cosf(fr);
  sinT[i] = sinf(fr);
}

// ---------------- RoPE apply in-place on qkv (Q: 32 heads, K: 8 heads) ----------------
__global__ void k_rope_apply(unsigned short* __restrict__ qkv, const float* __restrict__ cosT,
                             const float* __restrict__ sinT) {
  long i = (long)blockIdx.x * 256 + threadIdx.x;  // < M_ROWS*40*32
  int j = (int)(i & 31);
  long rem = i >> 5;
  int hs = (int)(rem % 40);
  long row = rem / 40;
  int t = (int)(row & (LSEQ - 1));
  long col = (hs < 32) ? (long)hs * 64 + j : (long)KOFF + (long)(hs - 32) * 64 + j;
  long base = row * NQKV + col;
  float v0 = bf2f(qkv[base]), v1 = bf2f(qkv[base + 32]);
  float c = cosT[t * 32 + j], s = sinT[t * 32 + j];
  qkv[base]      = f2bf(v0 * c - v1 * s);
  qkv[base + 32] = f2bf(v1 * c + v0 * s);
}

// ---------------- GEMM v3: 8-phase counted-vmcnt schedule (round-5, measured ~= 2-phase) ----------------
template<bool BF16OUT>
__global__ __launch_bounds__(512, 2) void k_gemm_8ph(
    const unsigned short* __restrict__ A, const unsigned short* __restrict__ Bt,
    void* __restrict__ Cv, int M, int N, int K, int nbn) {
  __shared__ __align__(16) char LDS[98304];   // A: [0,65536) ; B: [65536, 98304)
  int t = threadIdx.x;
  int lane = t & 63, wave = t >> 6;
  int fr = lane & 15, fg = lane >> 4;
  int wm = wave >> 2, wn = wave & 3;          // 2 M-waves x 4 N-waves
  int sw8 = (fr & 7) << 4;

  int nwg = (int)gridDim.x;
  int id = (int)blockIdx.x;
  int swz = (id & 7) * (nwg >> 3) + (id >> 3);
  long rowA = (long)(swz / nbn) * 256;
  long rowB = (long)(swz % nbn) * 128;

  long K2 = (long)K * 2;
  int scol = ((t & 7) * 16) ^ (((t >> 3) & 7) << 4);
  const char* Ab = (const char*)A;
  const char* Bb = (const char*)Bt;

  auto stageAh = [&](int kt, int h, int b) {
    #pragma unroll
    for (int q = 0; q < 2; q++)
      gload_lds16(Ab + (rowA + h * 128 + q * 64 + (t >> 3)) * K2 + kt * 128 + scol,
                  LDS + b * 32768 + h * 16384 + q * 8192 + t * 16);
  };
  auto stageBh = [&](int kt, int h, int b) {
    gload_lds16(Bb + (rowB + h * 64 + (t >> 3)) * K2 + kt * 128 + scol,
                LDS + 65536 + b * 16384 + h * 8192 + t * 16);
  };

  f32x4 acc[8][2] = {};

  auto rdA = [&](bf16x8 (&af)[4][2], int b, int qm) {
    #pragma unroll
    for (int i = 0; i < 4; i++) {
      #pragma unroll
      for (int ks = 0; ks < 2; ks++)
        af[i][ks] = *(const bf16x8*)(LDS + b * 32768 +
            (wm * 128 + qm * 64 + i * 16 + fr) * 128 + ((ks * 64 + fg * 16) ^ sw8));
    }
  };
  auto rdB = [&](bf16x8 (&bv)[2], int b, int qn) {
    #pragma unroll
    for (int ks = 0; ks < 2; ks++)
      bv[ks] = *(const bf16x8*)(LDS + 65536 + b * 16384 +
          (wn * 32 + qn * 16 + fr) * 128 + ((ks * 64 + fg * 16) ^ sw8));
  };
  auto quad = [&](bf16x8 (&af)[4][2], bf16x8 (&bv)[2], int qi, int qj) {
    __builtin_amdgcn_s_setprio(1);
    #pragma unroll
    for (int i = 0; i < 4; i++) {
      #pragma unroll
      for (int ks = 0; ks < 2; ks++)
        acc[qi * 4 + i][qj] =
            __builtin_amdgcn_mfma_f32_16x16x32_bf16(af[i][ks], bv[ks], acc[qi * 4 + i][qj], 0, 0, 0);
    }
    __builtin_amdgcn_s_setprio(0);
  };

  int NT = K >> 6;

  stageAh(0, 0, 0); stageAh(0, 1, 0); stageBh(0, 0, 0); stageBh(0, 1, 0);
  stageAh(1, 0, 1);
  __builtin_amdgcn_sched_barrier(0);
  asm volatile("s_waitcnt vmcnt(2)" ::: "memory");
  BARS;

  for (int u = 0; u < NT; u += 2) {
    bool pfw = (u + 2) < NT;
    bool pfx = (u + 3) < NT;
    bf16x8 a0[4][2], a1[4][2], b0[2], b1[2];

    // ---- K-tile u (buf0) ----
    rdA(a0, 0, 0); rdB(b0, 0, 0);
    stageAh(u + 1, 1, 1);
    BARS; quad(a0, b0, 0, 0); BARS;
    rdB(b1, 0, 1);
    stageBh(u + 1, 0, 1);
    BARS; quad(a0, b1, 0, 1); BARS;
    rdA(a1, 0, 1);
    stageBh(u + 1, 1, 1);
    BARS; quad(a1, b0, 1, 0); BARS;
    if (pfw) {
      stageAh(u + 2, 0, 0);
      __builtin_amdgcn_sched_barrier(0);
      asm volatile("s_waitcnt vmcnt(2)" ::: "memory");
    } else {
      asm volatile("s_waitcnt vmcnt(0)" ::: "memory");
    }
    BARS; quad(a1, b1, 1, 1); BARS;

    // ---- K-tile v = u+1 (buf1) ----
    rdA(a0, 1, 0); rdB(b0, 1, 0);
    if (pfw) stageAh(u + 2, 1, 0);
    BARS; quad(a0, b0, 0, 0); BARS;
    rdB(b1, 1, 1);
    if (pfw) stageBh(u + 2, 0, 0);
    BARS; quad(a0, b1, 0, 1); BARS;
    rdA(a1, 1, 1);
    if (pfw) stageBh(u + 2, 1, 0);
    BARS; quad(a1, b0, 1, 0); BARS;
    if (pfx) {
      stageAh(u + 3, 0, 1);
      __builtin_amdgcn_sched_barrier(0);
      asm volatile("s_waitcnt vmcnt(2)" ::: "memory");
    } else {
      asm volatile("s_waitcnt vmcnt(0)" ::: "memory");
    }
    BARS; quad(a1, b1, 1, 1); BARS;
  }

  #pragma unroll
  for (int ii = 0; ii < 8; ii++) {
    #pragma unroll
    for (int jj = 0; jj < 2; jj++) {
      #pragma unroll
      for (int r = 0; r < 4; r++) {
        long row = rowA + wm * 128 + ii * 16 + fg * 4 + r;
        long col = rowB + wn * 32 + jj * 16 + fr;
        if (BF16OUT) ((unsigned short*)Cv)[row * N + col] = f2bf(acc[ii][jj][r]);
        else         ((float*)Cv)[row * N + col] = acc[ii][jj][r];
      }
    }
  }
}

// ---------------- flash attention v16: in-register P, REGISTER-ONLY pack ----------------
// Round-7: v15's structure was correct (passed; bank-conflicts down) but the
// union{u[4];bf16x8} pack idiom defeated SROA -> alloca'd to SCRATCH (evidence:
// WRITE_SIZE 16.4->65.4MB, FETCH +18MB, VGPR 100->84 despite more live state).
// Fix: build the P fragments by static-index vector-element inserts -- pure
// subregister writes, no union, no memory. Identical bit layout (elem r = pe[r],
// elem 4+r = pq[r]); compiler can fuse cast pairs into v_cvt_pk_bf16_f32.
// Rest identical to v15: swapped QK (mfma(K,Q)) -> P lane-local per q-column;
// V k-order permuted in k_transpose_v to match A-frag slot order; LDS 48KB ->
// 3 blocks/CU; static-max softmax (wq pre-scaled into exp2 domain).
__global__ __launch_bounds__(256, 3) void k_flash_attn13(
    const unsigned short* __restrict__ qkv, const unsigned short* __restrict__ vT,
    unsigned short* __restrict__ attn) {
  int g0 = (int)blockIdx.x;
  int hb = g0 & 63;
  int h = hb & 31, b = hb >> 5;
  int qt = 15 - (g0 >> 6);            // heavy blocks first (backfill smooths the tail)
  int g = h >> 2;
  int t = threadIdx.x, lane = t & 63, wave = t >> 6;
  int fr = lane & 15, fg = lane >> 4;

  __shared__ __align__(16) char KT[16384];              // 16KB: K tile [128 rows][128B], swz
  __shared__ __align__(16) char VT2[2][16384];          // 32KB: V tile [64 rows][256B], swz, dbuf
  long rowbase = (long)b * LSEQ;

  int qbaseA = qt * 128 + wave * 32;
  int qbaseB = qbaseA + 16;

  const unsigned short* qpA = &qkv[(rowbase + qbaseA + fr) * NQKV + h * 64 + fg * 8];
  const unsigned short* qpB = &qkv[(rowbase + qbaseB + fr) * NQKV + h * 64 + fg * 8];
  bf16x8 qfA0 = *(const bf16x8*)(qpA);
  bf16x8 qfA1 = *(const bf16x8*)(qpA + 32);
  bf16x8 qfB0 = *(const bf16x8*)(qpB);
  bf16x8 qfB1 = *(const bf16x8*)(qpB + 32);

  int kcb = ((t & 7) * 16) ^ (((t >> 3) & 7) << 4);    // K: 128B rows, row = p*32 + (t>>3)
  int vcb = ((t & 15) * 16) ^ (((t >> 4) & 7) << 4);   // V: 256B rows, row = p*16 + (t>>4)

  const char* kgb = (const char*)qkv;
  const char* vgb = (const char*)vT;
  long ksrc0 = ((rowbase) * (long)NQKV + KOFF + (long)g * 64) * 2;
  long vsrc0 = (((long)(b * 512 + g * 64)) * LSEQ) * 2;

  auto stageK = [&](int kbase) {
    #pragma unroll
    for (int p = 0; p < 4; p++) {
      int krow = p * 32 + (t >> 3);
      gload_lds16(kgb + ksrc0 + (long)(kbase + krow) * (NQKV * 2) + kcb,
                  KT + p * 4096 + t * 16);
    }
  };
  auto stageV = [&](int kbase, char* dst) {
    #pragma unroll
    for (int p = 0; p < 4; p++) {
      int vrow = p * 16 + (t >> 4);
      gload_lds16(vgb + vsrc0 + (long)vrow * (LSEQ * 2) + kbase * 2 + vcb,
                  dst + p * 4096 + t * 16);
    }
  };

  stageK(0);
  stageV(0, VT2[0]);

  f32x4 poA[4] = {}, poB[4] = {};
  float lA = 0.f, lB = 0.f;   // per-lane partial denominators for q = qbase+fr

  int sw8 = (fr & 7) << 4;

  for (int kt = 0; kt <= qt; kt++) {
    int kbase = kt * 128;
    __syncthreads();   // B1: staged K/V landed; all waves' prev-iter LDS reads done

    // V restage WAR-safe at B1 (prev PV readers of this buffer synced); full-iter cover
    if (kt < qt) stageV(kbase + 128, VT2[(kt + 1) & 1]);

    f32x4 stA[8], stB[8];
    __builtin_amdgcn_s_setprio(1);
    #pragma unroll
    for (int s = 0; s < 8; s++) {
      const char* kr = KT + ((s * 16 + fr) << 7);
      bf16x8 kf0 = *(const bf16x8*)(kr + ((fg * 16) ^ sw8));
      bf16x8 kf1 = *(const bf16x8*)(kr + ((fg * 16 + 64) ^ sw8));
      f32x4 a = {};
      a = __builtin_amdgcn_mfma_f32_16x16x32_bf16(kf0, qfA0, a, 0, 0, 0);
      a = __builtin_amdgcn_mfma_f32_16x16x32_bf16(kf1, qfA1, a, 0, 0, 0);
      stA[s] = a;
      f32x4 c = {};
      c = __builtin_amdgcn_mfma_f32_16x16x32_bf16(kf0, qfB0, c, 0, 0, 0);
      c = __builtin_amdgcn_mfma_f32_16x16x32_bf16(kf1, qfB1, c, 0, 0, 0);
      stB[s] = c;
    }
    __builtin_amdgcn_s_setprio(0);
    __syncthreads();   // B2: all waves' K ds_reads retired -> K restage safe

    if (kt < qt) stageK(kbase + 128);   // lands by next B1; softmax+PV cover

    if (kt == qt) {   // diagonal tile: causal mask (k = kbase+s*16+fg*4+r, q = qbase+fr)
      #pragma unroll
      for (int s = 0; s < 8; s++) {
        #pragma unroll
        for (int r = 0; r < 4; r++) {
          int kp = kbase + s * 16 + fg * 4 + r;
          if (kp > qbaseA + fr) stA[s][r] = -1e30f;
          if (kp > qbaseB + fr) stB[s][r] = -1e30f;
        }
      }
    }

    // softmax (static-max, pre-scaled exp2 domain) + register-only bf16 pack.
    // A-frag slot (fg, j): j=r -> k32 = 4*fg + r ; j=4+r -> k32 = 16 + 4*fg + r.
    bf16x8 paA[4], paB[4];
    #pragma unroll
    for (int km = 0; km < 4; km++) {
      bf16x8 pa, pb;
      #pragma unroll
      for (int r = 0; r < 4; r++) {
        float peA = exp2f(stA[2 * km][r]);
        float pqA = exp2f(stA[2 * km + 1][r]);
        lA += peA + pqA;
        pa[r]     = (__bf16)peA;
        pa[r + 4] = (__bf16)pqA;
        float peB = exp2f(stB[2 * km][r]);
        float pqB = exp2f(stB[2 * km + 1][r]);
        lB += peB + pqB;
        pb[r]     = (__bf16)peB;
        pb[r + 4] = (__bf16)pqB;
      }
      paA[km] = pa;
      paB[km] = pb;
    }

    const char* Vb = VT2[kt & 1];
    __builtin_amdgcn_s_setprio(1);
    #pragma unroll
    for (int km = 0; km < 4; km++) {
      #pragma unroll
      for (int dt = 0; dt < 4; dt++) {
        const char* vr = Vb + ((dt * 16 + fr) << 8);
        bf16x8 vf = *(const bf16x8*)(vr + ((km * 64 + fg * 16) ^ sw8));
        poA[dt] = __builtin_amdgcn_mfma_f32_16x16x32_bf16(paA[km], vf, poA[dt], 0, 0, 0);
        poB[dt] = __builtin_amdgcn_mfma_f32_16x16x32_bf16(paB[km], vf, poB[dt], 0, 0, 0);
      }
    }
    __builtin_amdgcn_s_setprio(0);
    // no trailing barrier: next B1 orders LDS reads vs. restaging
  }

  // denominator: reduce per-lane partials over the fg-group (lanes fr, fr+16, fr+32, fr+48)
  lA += __shfl_xor(lA, 16, 64); lA += __shfl_xor(lA, 32, 64);
  lB += __shfl_xor(lB, 16, 64); lB += __shfl_xor(lB, 32, 64);

  // po[dt][r] is O[q = qbase + fg*4 + r][d = dt*16 + fr]; l for q-local i lives on lanes
  // with fr == i -> fetch via shfl from lane fg*4+r (fg=0 copy).
  #pragma unroll
  for (int r = 0; r < 4; r++) {
    float liA = 1.0f / __shfl(lA, fg * 4 + r, 64);
    float liB = 1.0f / __shfl(lB, fg * 4 + r, 64);
    #pragma unroll
    for (int dt = 0; dt < 4; dt++) {
      attn[(rowbase + qbaseA + fg * 4 + r) * DIM + h * 64 + dt * 16 + fr] = f2bf(poA[dt][r] * liA);
      attn[(rowbase + qbaseB + fg * 4 + r) * DIM + h * 64 + dt * 16 + fr] = f2bf(poB[dt][r] * liB);
    }
  }
}

extern "C" void kernel_launch(void* const* d_in, const int* in_sizes, int n_in,
                              void* d_out, int out_size, void* d_ws, size_t ws_size,
                              hipStream_t stream) {
  const float* x  = (const float*)d_in[0];
  const float* wq = (const float*)d_in[1];
  const float* wk = (const float*)d_in[2];
  const float* wv = (const float*)d_in[3];
  const float* wo = (const float*)d_in[4];

  char* ws = (char*)d_ws;
  unsigned short* xb    = (unsigned short*)(ws);                 // 16.78 MB (reused as vT later)
  unsigned short* wqkvT = (unsigned short*)(ws + 16777216);      // 12.58 MB [3072][2048]
  unsigned short* woT   = (unsigned short*)(ws + 29360128);      //  8.39 MB [2048][2048]
  unsigned short* qkv   = (unsigned short*)(ws + 37748736);      // 25.17 MB [4096][3072]
  unsigned short* attn  = (unsigned short*)(ws + 62914560);      // 16.78 MB [4096][2048]
  float* cosT           = (float*)(ws + 79691776);               // 256 KB
  float* sinT           = (float*)(ws + 79953920);               // 256 KB
  unsigned short* vT    = xb;                                    // alias: xb dead after QKV GEMM

  const float C2 = 0.125f * 1.44269504f;   // 1/sqrt(64) * log2(e), folded into wq

  k_cvt_x<<<8192, 256, 0, stream>>>(x, xb, M_ROWS * DIM / 4);
  dim3 tb(32, 8);
  k_transpose_bf16<<<dim3(DIM/32, DIM/32), tb, 0, stream>>>(wq, wqkvT, DIM, DIM, C2);
  k_transpose_bf16<<<dim3(512/32, DIM/32), tb, 0, stream>>>(wk, wqkvT + (long)2048*2048, DIM, 512, 1.0f);
  k_transpose_bf16<<<dim3(512/32, DIM/32), tb, 0, stream>>>(wv, wqkvT + (long)2560*2048, DIM, 512, 1.0f);
  k_transpose_bf16<<<dim3(DIM/32, DIM/32), tb, 0, stream>>>(wo, woT, DIM, DIM, 1.0f);
  k_rope_table<<<(LSEQ*32)/256, 256, 0, stream>>>(cosT, sinT);

  k_gemm_8ph<true><<<(M_ROWS/256)*(NQKV/128), 512, 0, stream>>>(xb, wqkvT, qkv, M_ROWS, NQKV, DIM, NQKV/128);
  k_rope_apply<<<(M_ROWS*40*32)/256, 256, 0, stream>>>(qkv, cosT, sinT);
  k_transpose_v<<<dim3(16, 64, 2), tb, 0, stream>>>(qkv, vT);
  k_flash_attn13<<<1024, 256, 0, stream>>>(qkv, vT, attn);
  k_gemm_8ph<false><<<(M_ROWS/256)*(DIM/128), 512, 0, stream>>>(attn, woT, d_out, M_ROWS, DIM, DIM, DIM/128);
}